// Round 1
// baseline (5511.089 us; speedup 1.0000x reference)
//
#include <hip/hip_runtime.h>
#include <math.h>

#define NN 50000
#define NE 800000
#define NGRAPH 100
#define NPG 500
#define NB_SCAN 196
#define CHAIN_ELEMS ((size_t)NN * 64)
#define CH4 ((size_t)NN * 16)          // float4 elements per plane
#define QF 16                          // floats per quarter row
#define QPLANE ((size_t)NN * QF)       // floats per quarter plane
#define GRID_P 2048                    // persistent prop grid (8 blocks/CU)
#define TOT_WAVES (GRID_P * 4)

typedef long long ll;

__device__ __forceinline__ void unpack(ll v, int& r, float& w) {
    r = (int)(v & 0xffffffffLL);
    w = __int_as_float((int)(v >> 32));
}

__device__ __forceinline__ float4 f4fma(float w, float4 v, float4 a) {
    a.x += w * v.x; a.y += w * v.y; a.z += w * v.z; a.w += w * v.w;
    return a;
}

// ---------------- setup kernels ----------------

__global__ void k_deg(const int* __restrict__ col, int* __restrict__ degi) {
    int e = blockIdx.x * blockDim.x + threadIdx.x;
    if (e < NE) atomicAdd(&degi[col[e]], 1);
}

__global__ void k_dh(const int* __restrict__ degi, float* __restrict__ dh) {
    int i = blockIdx.x * blockDim.x + threadIdx.x;
    if (i < NN) {
        int d = degi[i];
        dh[i] = d > 0 ? (float)(1.0 / sqrt((double)d)) : 0.0f;
    }
}

__global__ void k_bsum(const int* __restrict__ cnt, int* __restrict__ bsum) {
    __shared__ int sh[256];
    int i = blockIdx.x * 256 + threadIdx.x;
    sh[threadIdx.x] = (i < NN) ? cnt[i] : 0;
    __syncthreads();
    for (int s = 128; s > 0; s >>= 1) {
        if (threadIdx.x < s) sh[threadIdx.x] += sh[threadIdx.x + s];
        __syncthreads();
    }
    if (threadIdx.x == 0) bsum[blockIdx.x] = sh[0];
}

__global__ void k_bscan(const int* __restrict__ bsum, int* __restrict__ boff) {
    __shared__ int sh[2][256];
    int v = (threadIdx.x < NB_SCAN) ? bsum[threadIdx.x] : 0;
    int cur = 0;
    sh[0][threadIdx.x] = v;
    __syncthreads();
    for (int s = 1; s < 256; s <<= 1) {
        int val = sh[cur][threadIdx.x];
        if ((int)threadIdx.x >= s) val += sh[cur][threadIdx.x - s];
        sh[cur ^ 1][threadIdx.x] = val;
        cur ^= 1;
        __syncthreads();
    }
    if (threadIdx.x < NB_SCAN) boff[threadIdx.x] = sh[cur][threadIdx.x] - v;
}

__global__ void k_scan2(const int* __restrict__ cnt, const int* __restrict__ boff,
                        int* __restrict__ off) {
    __shared__ int sh[2][256];
    int i = blockIdx.x * 256 + threadIdx.x;
    int v = (i < NN) ? cnt[i] : 0;
    int cur = 0;
    sh[0][threadIdx.x] = v;
    __syncthreads();
    for (int s = 1; s < 256; s <<= 1) {
        int val = sh[cur][threadIdx.x];
        if ((int)threadIdx.x >= s) val += sh[cur][threadIdx.x - s];
        sh[cur ^ 1][threadIdx.x] = val;
        cur ^= 1;
        __syncthreads();
    }
    if (i < NN) off[i] = boff[blockIdx.x] + sh[cur][threadIdx.x] - v;
}

__global__ void k_fill(const int* __restrict__ row, const int* __restrict__ col,
                       const float* __restrict__ dh, const int* __restrict__ off,
                       int* __restrict__ cursor, ll* __restrict__ csrp) {
    int e = blockIdx.x * blockDim.x + threadIdx.x;
    if (e >= NE) return;
    int r = row[e], c = col[e];
    int pos = off[c] + atomicAdd(&cursor[c], 1);
    float w = dh[r] * dh[c];
    csrp[pos] = ((ll)__float_as_int(w) << 32) | (unsigned int)r;
}

// transpose x[NN][64] -> xq[4][NN][16] (quarter-major), one float4 per thread
__global__ void k_xpose(const float* __restrict__ x, float* __restrict__ xq) {
    size_t o = (size_t)blockIdx.x * 256 + threadIdx.x;   // float4 index < CH4
    size_t q = o / ((size_t)NN * 4);
    size_t rem = o - q * ((size_t)NN * 4);
    size_t n = rem >> 2;
    size_t j = rem & 3;
    float4 v = *(const float4*)&x[n * 64 + q * QF + j * 4];
    ((float4*)xq)[o] = v;
}

// ---------------- recurrence kernel ----------------
// Quarter-major persistent prop. The 64 features are 4 independent 16-float
// chains; processing quarter-by-quarter keeps the active gather table at
// 3.2 MB (fits per-XCD 4 MB L2). wave = node; lane = eg*4 + cq:
// eg = edge slot (0..15), cq = float4 within the 16-float quarter row.
// Streams (csrp, Tprev) use non-temporal loads so the table stays L2-resident.

template <bool INIT>
__global__ __launch_bounds__(256, 8) void k_prop(
    const float* __restrict__ Tcur, const float* __restrict__ Tprev,
    float* __restrict__ Tnext, const int* __restrict__ off,
    const int* __restrict__ degi, const ll* __restrict__ csrp) {
    int wave = blockIdx.x * 4 + (threadIdx.x >> 6);
    int lane = threadIdx.x & 63;
    int eg = lane >> 2;
    int cq = lane & 3;
    for (int q = 0; q < 4; ++q) {
        const float* tb = Tcur + (size_t)q * QPLANE + cq * 4;
        for (int node = wave; node < NN; node += TOT_WAVES) {
            int s = off[node], e = s + degi[node];
            float4 a = make_float4(0.f, 0.f, 0.f, 0.f);
            for (int i = s; i < e; i += 16) {
                int idx = i + eg;
                bool act = idx < e;
                ll pk = __builtin_nontemporal_load(&csrp[act ? idx : (e - 1)]);
                int r; float w;
                unpack(pk, r, w);
                if (!act) w = 0.f;
                float4 v = *(const float4*)(tb + (size_t)r * QF);
                a = f4fma(w, v, a);
            }
            // reduce over eg (lanes differing in bits 2..5)
            a.x += __shfl_xor(a.x, 4);  a.y += __shfl_xor(a.y, 4);
            a.z += __shfl_xor(a.z, 4);  a.w += __shfl_xor(a.w, 4);
            a.x += __shfl_xor(a.x, 8);  a.y += __shfl_xor(a.y, 8);
            a.z += __shfl_xor(a.z, 8);  a.w += __shfl_xor(a.w, 8);
            a.x += __shfl_xor(a.x, 16); a.y += __shfl_xor(a.y, 16);
            a.z += __shfl_xor(a.z, 16); a.w += __shfl_xor(a.w, 16);
            a.x += __shfl_xor(a.x, 32); a.y += __shfl_xor(a.y, 32);
            a.z += __shfl_xor(a.z, 32); a.w += __shfl_xor(a.w, 32);
            if (lane < 4) {
                size_t o = (size_t)q * QPLANE + (size_t)node * QF + cq * 4;
                float4 t;
                if (INIT) {
                    t = make_float4(-a.x, -a.y, -a.z, -a.w);
                } else {
                    const float* pp = Tprev + o;
                    float px = __builtin_nontemporal_load(pp + 0);
                    float py = __builtin_nontemporal_load(pp + 1);
                    float pz = __builtin_nontemporal_load(pp + 2);
                    float pw = __builtin_nontemporal_load(pp + 3);
                    t = make_float4(-2.f * a.x - px, -2.f * a.y - py,
                                    -2.f * a.z - pz, -2.f * a.w - pw);
                }
                *(float4*)&Tnext[o] = t;
            }
        }
    }
}

// ---------------- combine: acc planes from NS pool slots (float4) -----------
// Planes are quarter-major now, but combine is elementwise on flat arrays, so
// logic is unchanged.

struct CombCfg {
    float c0[4];
    float ck[4][8];
    int   plane[4];
};

template <int NS, int NT>
__global__ __launch_bounds__(256) void k_combine(
    const float4* __restrict__ src0, const float4* __restrict__ pool,
    float4* __restrict__ accb, CombCfg cfg, int first, int doabs) {
    size_t v = (size_t)blockIdx.x * 256 + threadIdx.x;   // < NN*16
    float4 tv[NS];
#pragma unroll
    for (int m = 0; m < NS; ++m) tv[m] = pool[(size_t)m * CH4 + v];
    float4 s0 = first ? src0[v] : make_float4(0.f, 0.f, 0.f, 0.f);
#pragma unroll
    for (int t = 0; t < NT; ++t) {
        size_t o = (size_t)cfg.plane[t] * CH4 + v;
        float4 a;
        if (first) {
            float c = cfg.c0[t];
            a = make_float4(c * s0.x, c * s0.y, c * s0.z, c * s0.w);
        } else {
            a = accb[o];
        }
#pragma unroll
        for (int m = 0; m < NS; ++m) a = f4fma(cfg.ck[t][m], tv[m], a);
        if (doabs) a = make_float4(fabsf(a.x), fabsf(a.y), fabsf(a.z), fabsf(a.w));
        accb[o] = a;
    }
}

// ---------------- moments (quarter-major addressing) ----------------
__global__ void k_moments(const float* __restrict__ xq, const float* __restrict__ hacc,
                          const float* __restrict__ acc2, float* __restrict__ out) {
    int g = blockIdx.y;
    int col = blockIdx.x * 256 + threadIdx.x;
    if (col >= 704) return;
    const float* src;
    int c0;
    if (col < 64)       { src = xq;   c0 = col; }
    else if (col < 320) { int p = (col - 64) >> 6;  src = hacc + (size_t)p * CHAIN_ELEMS; c0 = (col - 64) & 63; }
    else                { int p = (col - 320) >> 6; src = acc2 + (size_t)p * CHAIN_ELEMS; c0 = (col - 320) & 63; }
    const float* sp = src + (size_t)(c0 >> 4) * QPLANE + (c0 & 15);
    double s1 = 0, s2 = 0, s3 = 0, s4 = 0;
    int base = g * NPG;
    for (int i = 0; i < NPG; ++i) {
        double v = (double)sp[(size_t)(base + i) * QF];
        double v2 = v * v;
        s1 += v; s2 += v2; s3 += v2 * v; s4 += v2 * v2;
    }
    double n = (double)NPG;
    double mu = s1 / n;
    double E2 = s2 / n, E3 = s3 / n, E4 = s4 / n;
    double m2 = E2 - mu * mu;
    double m3 = E3 - 3.0 * mu * E2 + 2.0 * mu * mu * mu;
    double m4 = E4 - 4.0 * mu * E3 + 6.0 * mu * mu * E2 - 3.0 * mu * mu * mu * mu;
    float m2f = (float)m2;
    float skew = 0.f, kurt = -3.f;
    if (m2f > 0.f) {
        skew = (float)(m3 / (m2 * sqrt(m2)));
        if (skew > 1e15f) skew = 0.f;
        kurt = (float)(m4 / (m2 * m2) - 3.0);
        if (kurt > 1e15f) kurt = -3.f;
    }
    size_t ob = (size_t)g * 2816 + col;
    out[ob]        = (float)mu;
    out[ob + 704]  = m2f;
    out[ob + 1408] = skew;
    out[ob + 2112] = kurt;
}

// ---------------- host ----------------

extern "C" void kernel_launch(void* const* d_in, const int* in_sizes, int n_in,
                              void* d_out, int out_size, void* d_ws, size_t ws_size,
                              hipStream_t stream) {
    const float* x = (const float*)d_in[0];
    const int* ei  = (const int*)d_in[1];
    const int* row = ei;
    const int* col = ei + NE;
    float* out = (float*)d_out;

    // Chebyshev coefficients [17][4], double precision (matches numpy)
    float C[17][4];
    {
        const int Nc = 17;
        const int scales[4] = {2, 4, 8, 16};
        for (int si = 0; si < 4; ++si) {
            double ker[17];
            for (int j = 0; j < Nc; ++j) {
                double num = cos(M_PI * (j + 0.5) / Nc);
                double b = -num;
                double v = pow(b, (double)(scales[si] / 2)) - pow(b, (double)scales[si]);
                if (v < 0) v = 0;
                ker[j] = sqrt(v);
            }
            for (int o = 0; o < Nc; ++o) {
                double acc = 0;
                for (int j = 0; j < Nc; ++j) acc += ker[j] * cos(M_PI * o * (j + 0.5) / Nc);
                C[o][si] = (float)(2.0 / Nc * acc);
            }
        }
    }

    // workspace carve: 8-slot pool; fallback 4
    int*   degi; float* dh; int* off; int* cursor; int* bsum; int* boff;
    ll*    csrp; float* pool; float* hacc; float* acc2; float* xq;
    int SLOTS = 8;
    for (int attempt = 0; attempt < 2; ++attempt) {
        char* p = (char*)d_ws;
        auto alloc = [&](size_t bytes) -> void* {
            void* r = (void*)p;
            p += (bytes + 255) & ~(size_t)255;
            return r;
        };
        degi   = (int*)alloc((size_t)NN * 4);
        dh     = (float*)alloc((size_t)NN * 4);
        off    = (int*)alloc((size_t)NN * 4);
        cursor = (int*)alloc((size_t)NN * 4);
        bsum   = (int*)alloc((size_t)NB_SCAN * 4);
        boff   = (int*)alloc((size_t)NB_SCAN * 4);
        csrp   = (ll*)alloc((size_t)NE * 8);
        xq     = (float*)alloc(CHAIN_ELEMS * 4);
        pool   = (float*)alloc((size_t)SLOTS * CHAIN_ELEMS * 4);
        hacc   = (float*)alloc((size_t)4 * CHAIN_ELEMS * 4);
        acc2   = (float*)alloc((size_t)6 * CHAIN_ELEMS * 4);
        if ((size_t)(p - (char*)d_ws) <= ws_size) break;
        SLOTS = 4;
    }
    const int CAD = SLOTS;   // combine cadence

    hipMemsetAsync(degi, 0, (size_t)NN * 4, stream);
    hipMemsetAsync(cursor, 0, (size_t)NN * 4, stream);

    k_deg  <<<(NE + 255) / 256, 256, 0, stream>>>(col, degi);
    k_dh   <<<(NN + 255) / 256, 256, 0, stream>>>(degi, dh);
    k_bsum <<<NB_SCAN, 256, 0, stream>>>(degi, bsum);
    k_bscan<<<1, 256, 0, stream>>>(bsum, boff);
    k_scan2<<<NB_SCAN, 256, 0, stream>>>(degi, boff, off);
    k_fill <<<(NE + 255) / 256, 256, 0, stream>>>(row, col, dh, off, cursor, csrp);

    const int GRID_C = (int)(CH4 / 256);   // 3125
    k_xpose<<<GRID_C, 256, 0, stream>>>(x, xq);

    auto slot = [&](int k) { return pool + (size_t)((k - 1) & (SLOTS - 1)) * CHAIN_ELEMS; };

    auto launch_combine = [&](int nt, const float* src, float* accb,
                              CombCfg& cfg, int first, int doabs) {
        const float4* s4 = (const float4*)src;
        const float4* p4 = (const float4*)pool;
        float4* a4 = (float4*)accb;
        if (CAD == 8) {
            if (nt == 4) k_combine<8, 4><<<GRID_C, 256, 0, stream>>>(s4, p4, a4, cfg, first, doabs);
            if (nt == 3) k_combine<8, 3><<<GRID_C, 256, 0, stream>>>(s4, p4, a4, cfg, first, doabs);
            if (nt == 2) k_combine<8, 2><<<GRID_C, 256, 0, stream>>>(s4, p4, a4, cfg, first, doabs);
            if (nt == 1) k_combine<8, 1><<<GRID_C, 256, 0, stream>>>(s4, p4, a4, cfg, first, doabs);
        } else {
            if (nt == 4) k_combine<4, 4><<<GRID_C, 256, 0, stream>>>(s4, p4, a4, cfg, first, doabs);
            if (nt == 3) k_combine<4, 3><<<GRID_C, 256, 0, stream>>>(s4, p4, a4, cfg, first, doabs);
            if (nt == 2) k_combine<4, 2><<<GRID_C, 256, 0, stream>>>(s4, p4, a4, cfg, first, doabs);
            if (nt == 1) k_combine<4, 1><<<GRID_C, 256, 0, stream>>>(s4, p4, a4, cfg, first, doabs);
        }
    };

    // run one chain: src (quarter-major [4][NN][16]) -> acc planes of accb
    auto run_chain = [&](const float* src, float* accb,
                         const int* scl, const int* pln, int nt) {
        k_prop<true><<<GRID_P, 256, 0, stream>>>(src, nullptr, slot(1),
                                                 off, degi, csrp);
        for (int k = 2; k <= 16; ++k) {
            const float* Tprev = (k == 2) ? src : slot(k - 2);
            k_prop<false><<<GRID_P, 256, 0, stream>>>(slot(k - 1), Tprev, slot(k),
                                                      off, degi, csrp);
            if ((k % CAD) == 0) {
                CombCfg cfg;
                for (int t = 0; t < nt; ++t) {
                    int si = scl[t];
                    cfg.c0[t] = 0.5f * C[0][si];
                    cfg.plane[t] = pln[t];
                    for (int m = 0; m < CAD; ++m) cfg.ck[t][m] = C[k - CAD + 1 + m][si];
                }
                launch_combine(nt, src, accb, cfg, (k == CAD) ? 1 : 0,
                               (k == 16) ? 1 : 0);
            }
        }
    };

    // ---- phase 1: xq -> hacc planes 0..3 (|h| per scale) ----
    {
        const int scl[4] = {0, 1, 2, 3};
        const int pln[4] = {0, 1, 2, 3};
        run_chain(xq, hacc, scl, pln, 4);
    }

    // ---- phase 2: 3 chains on hacc planes 0..2 ----
    {
        const int scl0[3] = {1, 2, 3}; const int pln0[3] = {0, 1, 3};
        run_chain(hacc + 0 * CHAIN_ELEMS, acc2, scl0, pln0, 3);
        const int scl1[2] = {2, 3};    const int pln1[2] = {2, 4};
        run_chain(hacc + 1 * CHAIN_ELEMS, acc2, scl1, pln1, 2);
        const int scl2[1] = {3};       const int pln2[1] = {5};
        run_chain(hacc + 2 * CHAIN_ELEMS, acc2, scl2, pln2, 1);
    }

    // ---- moments ----
    dim3 mg(3, NGRAPH);
    k_moments<<<mg, 256, 0, stream>>>(xq, hacc, acc2, out);
}

// Round 2
// 3314.941 us; speedup vs baseline: 1.6625x; 1.6625x over previous
//
#include <hip/hip_runtime.h>
#include <math.h>

#define NN 50000
#define NE 800000
#define NGRAPH 100
#define NPG 500
#define NB_SCAN 196
#define CHAIN_ELEMS ((size_t)NN * 64)
#define CH4 ((size_t)NN * 16)          // float4 elements per plane
#define QF 16                          // floats per quarter row
#define QPLANE ((size_t)NN * QF)       // floats per quarter plane
#define GRID_P 2048                    // persistent prop grid (8 blocks/CU)
#define QWAVES 2048                    // waves per quarter (512 blocks * 4)

typedef long long ll;
typedef float f32x4_t __attribute__((ext_vector_type(4)));

__device__ __forceinline__ void unpack(ll v, int& r, float& w) {
    r = (int)(v & 0xffffffffLL);
    w = __int_as_float((int)(v >> 32));
}

__device__ __forceinline__ float4 f4fma(float w, float4 v, float4 a) {
    a.x += w * v.x; a.y += w * v.y; a.z += w * v.z; a.w += w * v.w;
    return a;
}

// ---------------- setup kernels ----------------

__global__ void k_deg(const int* __restrict__ col, int* __restrict__ degi) {
    int e = blockIdx.x * blockDim.x + threadIdx.x;
    if (e < NE) atomicAdd(&degi[col[e]], 1);
}

__global__ void k_dh(const int* __restrict__ degi, float* __restrict__ dh) {
    int i = blockIdx.x * blockDim.x + threadIdx.x;
    if (i < NN) {
        int d = degi[i];
        dh[i] = d > 0 ? (float)(1.0 / sqrt((double)d)) : 0.0f;
    }
}

__global__ void k_bsum(const int* __restrict__ cnt, int* __restrict__ bsum) {
    __shared__ int sh[256];
    int i = blockIdx.x * 256 + threadIdx.x;
    sh[threadIdx.x] = (i < NN) ? cnt[i] : 0;
    __syncthreads();
    for (int s = 128; s > 0; s >>= 1) {
        if (threadIdx.x < s) sh[threadIdx.x] += sh[threadIdx.x + s];
        __syncthreads();
    }
    if (threadIdx.x == 0) bsum[blockIdx.x] = sh[0];
}

__global__ void k_bscan(const int* __restrict__ bsum, int* __restrict__ boff) {
    __shared__ int sh[2][256];
    int v = (threadIdx.x < NB_SCAN) ? bsum[threadIdx.x] : 0;
    int cur = 0;
    sh[0][threadIdx.x] = v;
    __syncthreads();
    for (int s = 1; s < 256; s <<= 1) {
        int val = sh[cur][threadIdx.x];
        if ((int)threadIdx.x >= s) val += sh[cur][threadIdx.x - s];
        sh[cur ^ 1][threadIdx.x] = val;
        cur ^= 1;
        __syncthreads();
    }
    if (threadIdx.x < NB_SCAN) boff[threadIdx.x] = sh[cur][threadIdx.x] - v;
}

__global__ void k_scan2(const int* __restrict__ cnt, const int* __restrict__ boff,
                        int* __restrict__ off) {
    __shared__ int sh[2][256];
    int i = blockIdx.x * 256 + threadIdx.x;
    int v = (i < NN) ? cnt[i] : 0;
    int cur = 0;
    sh[0][threadIdx.x] = v;
    __syncthreads();
    for (int s = 1; s < 256; s <<= 1) {
        int val = sh[cur][threadIdx.x];
        if ((int)threadIdx.x >= s) val += sh[cur][threadIdx.x - s];
        sh[cur ^ 1][threadIdx.x] = val;
        cur ^= 1;
        __syncthreads();
    }
    if (i < NN) off[i] = boff[blockIdx.x] + sh[cur][threadIdx.x] - v;
}

__global__ void k_fill(const int* __restrict__ row, const int* __restrict__ col,
                       const float* __restrict__ dh, const int* __restrict__ off,
                       int* __restrict__ cursor, ll* __restrict__ csrp) {
    int e = blockIdx.x * blockDim.x + threadIdx.x;
    if (e >= NE) return;
    int r = row[e], c = col[e];
    int pos = off[c] + atomicAdd(&cursor[c], 1);
    float w = dh[r] * dh[c];
    csrp[pos] = ((ll)__float_as_int(w) << 32) | (unsigned int)r;
}

// transpose x[NN][64] -> xq[4][NN][16] (quarter-major), one float4 per thread
__global__ void k_xpose(const float* __restrict__ x, float* __restrict__ xq) {
    size_t o = (size_t)blockIdx.x * 256 + threadIdx.x;   // float4 index < CH4
    size_t q = o / ((size_t)NN * 4);
    size_t rem = o - q * ((size_t)NN * 4);
    size_t n = rem >> 2;
    size_t j = rem & 3;
    float4 v = *(const float4*)&x[n * 64 + q * QF + j * 4];
    ((float4*)xq)[o] = v;
}

// ---------------- recurrence kernel ----------------
// Quarter-major, quarter-per-XCD-pair. blocks dispatch round-robin over the
// 8 XCDs; q = (blockIdx&7)>>1 so each XCD pair sweeps ALL nodes of ONE
// quarter -> active gather table 3.2 MB (per-XCD L2 fit) and table
// duplication drops 8x -> 2x (locality heuristic only; coverage/correctness
// are mapping-independent).
// wave = 4 nodes. lane = ns*16 + eg*4 + cq: ns = node sub, eg = edge slot,
// cq = float4 within 64 B quarter row. Edge loop = round-0's validated
// 8-deep / 2-accumulator shape; reduce = 2 shuffle stages (xor 4, 8).
// Streams (csrp, Tprev, Tnext) nontemporal so the gather table stays in L2.

template <bool INIT>
__global__ __launch_bounds__(256, 8) void k_prop(
    const float* __restrict__ Tcur, const float* __restrict__ Tprev,
    float* __restrict__ Tnext, const int* __restrict__ off,
    const int* __restrict__ degi, const ll* __restrict__ csrp) {
    int lane = threadIdx.x & 63;
    int ns = lane >> 4;
    int eg = (lane >> 2) & 3;
    int cq = lane & 3;
    int xcd = blockIdx.x & 7;
    int q = xcd >> 1;
    int wv = ((((blockIdx.x >> 3) << 1) | (xcd & 1)) << 2) + (threadIdx.x >> 6);
    const float* tb = Tcur + (size_t)q * QPLANE + cq * 4;
    for (int g0 = wv * 4; g0 < NN; g0 += QWAVES * 4) {
        int node = g0 + ns;
        bool nact = node < NN;
        int s = nact ? off[node] : 0;
        int e = nact ? s + degi[node] : 0;
        float4 a0 = make_float4(0.f, 0.f, 0.f, 0.f);
        float4 a1 = make_float4(0.f, 0.f, 0.f, 0.f);
        int i = s;
        for (; i + 8 <= e; i += 8) {
            int r0, r1; float w0, w1;
            unpack(__builtin_nontemporal_load(&csrp[i + eg]), r0, w0);
            unpack(__builtin_nontemporal_load(&csrp[i + 4 + eg]), r1, w1);
            float4 v0 = *(const float4*)(tb + (size_t)r0 * QF);
            float4 v1 = *(const float4*)(tb + (size_t)r1 * QF);
            a0 = f4fma(w0, v0, a0);
            a1 = f4fma(w1, v1, a1);
        }
        for (; i < e; i += 4) {
            int idx = i + eg;
            bool act = idx < e;
            int r; float w;
            unpack(__builtin_nontemporal_load(&csrp[act ? idx : (e - 1)]), r, w);
            if (!act) w = 0.f;
            float4 v = *(const float4*)(tb + (size_t)r * QF);
            a0 = f4fma(w, v, a0);
        }
        float4 a = make_float4(a0.x + a1.x, a0.y + a1.y, a0.z + a1.z, a0.w + a1.w);
        a.x += __shfl_xor(a.x, 4); a.y += __shfl_xor(a.y, 4);
        a.z += __shfl_xor(a.z, 4); a.w += __shfl_xor(a.w, 4);
        a.x += __shfl_xor(a.x, 8); a.y += __shfl_xor(a.y, 8);
        a.z += __shfl_xor(a.z, 8); a.w += __shfl_xor(a.w, 8);
        if (((lane & 12) == 0) && nact) {
            size_t o = (size_t)q * QPLANE + (size_t)node * QF + cq * 4;
            f32x4_t t;
            if (INIT) {
                t.x = -a.x; t.y = -a.y; t.z = -a.z; t.w = -a.w;
            } else {
                f32x4_t pv = __builtin_nontemporal_load((const f32x4_t*)(Tprev + o));
                t.x = -2.f * a.x - pv.x; t.y = -2.f * a.y - pv.y;
                t.z = -2.f * a.z - pv.z; t.w = -2.f * a.w - pv.w;
            }
            __builtin_nontemporal_store(t, (f32x4_t*)(Tnext + o));
        }
    }
}

// ---------------- combine: acc planes from NS pool slots (float4) -----------
// Planes are quarter-major, but combine is elementwise on flat arrays, so
// logic is unchanged.

struct CombCfg {
    float c0[4];
    float ck[4][8];
    int   plane[4];
};

template <int NS, int NT>
__global__ __launch_bounds__(256) void k_combine(
    const float4* __restrict__ src0, const float4* __restrict__ pool,
    float4* __restrict__ accb, CombCfg cfg, int first, int doabs) {
    size_t v = (size_t)blockIdx.x * 256 + threadIdx.x;   // < NN*16
    float4 tv[NS];
#pragma unroll
    for (int m = 0; m < NS; ++m) tv[m] = pool[(size_t)m * CH4 + v];
    float4 s0 = first ? src0[v] : make_float4(0.f, 0.f, 0.f, 0.f);
#pragma unroll
    for (int t = 0; t < NT; ++t) {
        size_t o = (size_t)cfg.plane[t] * CH4 + v;
        float4 a;
        if (first) {
            float c = cfg.c0[t];
            a = make_float4(c * s0.x, c * s0.y, c * s0.z, c * s0.w);
        } else {
            a = accb[o];
        }
#pragma unroll
        for (int m = 0; m < NS; ++m) a = f4fma(cfg.ck[t][m], tv[m], a);
        if (doabs) a = make_float4(fabsf(a.x), fabsf(a.y), fabsf(a.z), fabsf(a.w));
        accb[o] = a;
    }
}

// ---------------- moments (quarter-major addressing) ----------------
__global__ void k_moments(const float* __restrict__ xq, const float* __restrict__ hacc,
                          const float* __restrict__ acc2, float* __restrict__ out) {
    int g = blockIdx.y;
    int col = blockIdx.x * 256 + threadIdx.x;
    if (col >= 704) return;
    const float* src;
    int c0;
    if (col < 64)       { src = xq;   c0 = col; }
    else if (col < 320) { int p = (col - 64) >> 6;  src = hacc + (size_t)p * CHAIN_ELEMS; c0 = (col - 64) & 63; }
    else                { int p = (col - 320) >> 6; src = acc2 + (size_t)p * CHAIN_ELEMS; c0 = (col - 320) & 63; }
    const float* sp = src + (size_t)(c0 >> 4) * QPLANE + (c0 & 15);
    double s1 = 0, s2 = 0, s3 = 0, s4 = 0;
    int base = g * NPG;
    for (int i = 0; i < NPG; ++i) {
        double v = (double)sp[(size_t)(base + i) * QF];
        double v2 = v * v;
        s1 += v; s2 += v2; s3 += v2 * v; s4 += v2 * v2;
    }
    double n = (double)NPG;
    double mu = s1 / n;
    double E2 = s2 / n, E3 = s3 / n, E4 = s4 / n;
    double m2 = E2 - mu * mu;
    double m3 = E3 - 3.0 * mu * E2 + 2.0 * mu * mu * mu;
    double m4 = E4 - 4.0 * mu * E3 + 6.0 * mu * mu * E2 - 3.0 * mu * mu * mu * mu;
    float m2f = (float)m2;
    float skew = 0.f, kurt = -3.f;
    if (m2f > 0.f) {
        skew = (float)(m3 / (m2 * sqrt(m2)));
        if (skew > 1e15f) skew = 0.f;
        kurt = (float)(m4 / (m2 * m2) - 3.0);
        if (kurt > 1e15f) kurt = -3.f;
    }
    size_t ob = (size_t)g * 2816 + col;
    out[ob]        = (float)mu;
    out[ob + 704]  = m2f;
    out[ob + 1408] = skew;
    out[ob + 2112] = kurt;
}

// ---------------- host ----------------

extern "C" void kernel_launch(void* const* d_in, const int* in_sizes, int n_in,
                              void* d_out, int out_size, void* d_ws, size_t ws_size,
                              hipStream_t stream) {
    const float* x = (const float*)d_in[0];
    const int* ei  = (const int*)d_in[1];
    const int* row = ei;
    const int* col = ei + NE;
    float* out = (float*)d_out;

    // Chebyshev coefficients [17][4], double precision (matches numpy)
    float C[17][4];
    {
        const int Nc = 17;
        const int scales[4] = {2, 4, 8, 16};
        for (int si = 0; si < 4; ++si) {
            double ker[17];
            for (int j = 0; j < Nc; ++j) {
                double num = cos(M_PI * (j + 0.5) / Nc);
                double b = -num;
                double v = pow(b, (double)(scales[si] / 2)) - pow(b, (double)scales[si]);
                if (v < 0) v = 0;
                ker[j] = sqrt(v);
            }
            for (int o = 0; o < Nc; ++o) {
                double acc = 0;
                for (int j = 0; j < Nc; ++j) acc += ker[j] * cos(M_PI * o * (j + 0.5) / Nc);
                C[o][si] = (float)(2.0 / Nc * acc);
            }
        }
    }

    // workspace carve: 8-slot pool; fallback 4
    int*   degi; float* dh; int* off; int* cursor; int* bsum; int* boff;
    ll*    csrp; float* pool; float* hacc; float* acc2; float* xq;
    int SLOTS = 8;
    for (int attempt = 0; attempt < 2; ++attempt) {
        char* p = (char*)d_ws;
        auto alloc = [&](size_t bytes) -> void* {
            void* r = (void*)p;
            p += (bytes + 255) & ~(size_t)255;
            return r;
        };
        degi   = (int*)alloc((size_t)NN * 4);
        dh     = (float*)alloc((size_t)NN * 4);
        off    = (int*)alloc((size_t)NN * 4);
        cursor = (int*)alloc((size_t)NN * 4);
        bsum   = (int*)alloc((size_t)NB_SCAN * 4);
        boff   = (int*)alloc((size_t)NB_SCAN * 4);
        csrp   = (ll*)alloc((size_t)NE * 8);
        xq     = (float*)alloc(CHAIN_ELEMS * 4);
        pool   = (float*)alloc((size_t)SLOTS * CHAIN_ELEMS * 4);
        hacc   = (float*)alloc((size_t)4 * CHAIN_ELEMS * 4);
        acc2   = (float*)alloc((size_t)6 * CHAIN_ELEMS * 4);
        if ((size_t)(p - (char*)d_ws) <= ws_size) break;
        SLOTS = 4;
    }
    const int CAD = SLOTS;   // combine cadence

    hipMemsetAsync(degi, 0, (size_t)NN * 4, stream);
    hipMemsetAsync(cursor, 0, (size_t)NN * 4, stream);

    k_deg  <<<(NE + 255) / 256, 256, 0, stream>>>(col, degi);
    k_dh   <<<(NN + 255) / 256, 256, 0, stream>>>(degi, dh);
    k_bsum <<<NB_SCAN, 256, 0, stream>>>(degi, bsum);
    k_bscan<<<1, 256, 0, stream>>>(bsum, boff);
    k_scan2<<<NB_SCAN, 256, 0, stream>>>(degi, boff, off);
    k_fill <<<(NE + 255) / 256, 256, 0, stream>>>(row, col, dh, off, cursor, csrp);

    const int GRID_C = (int)(CH4 / 256);   // 3125
    k_xpose<<<GRID_C, 256, 0, stream>>>(x, xq);

    auto slot = [&](int k) { return pool + (size_t)((k - 1) & (SLOTS - 1)) * CHAIN_ELEMS; };

    auto launch_combine = [&](int nt, const float* src, float* accb,
                              CombCfg& cfg, int first, int doabs) {
        const float4* s4 = (const float4*)src;
        const float4* p4 = (const float4*)pool;
        float4* a4 = (float4*)accb;
        if (CAD == 8) {
            if (nt == 4) k_combine<8, 4><<<GRID_C, 256, 0, stream>>>(s4, p4, a4, cfg, first, doabs);
            if (nt == 3) k_combine<8, 3><<<GRID_C, 256, 0, stream>>>(s4, p4, a4, cfg, first, doabs);
            if (nt == 2) k_combine<8, 2><<<GRID_C, 256, 0, stream>>>(s4, p4, a4, cfg, first, doabs);
            if (nt == 1) k_combine<8, 1><<<GRID_C, 256, 0, stream>>>(s4, p4, a4, cfg, first, doabs);
        } else {
            if (nt == 4) k_combine<4, 4><<<GRID_C, 256, 0, stream>>>(s4, p4, a4, cfg, first, doabs);
            if (nt == 3) k_combine<4, 3><<<GRID_C, 256, 0, stream>>>(s4, p4, a4, cfg, first, doabs);
            if (nt == 2) k_combine<4, 2><<<GRID_C, 256, 0, stream>>>(s4, p4, a4, cfg, first, doabs);
            if (nt == 1) k_combine<4, 1><<<GRID_C, 256, 0, stream>>>(s4, p4, a4, cfg, first, doabs);
        }
    };

    // run one chain: src (quarter-major [4][NN][16]) -> acc planes of accb
    auto run_chain = [&](const float* src, float* accb,
                         const int* scl, const int* pln, int nt) {
        k_prop<true><<<GRID_P, 256, 0, stream>>>(src, nullptr, slot(1),
                                                 off, degi, csrp);
        for (int k = 2; k <= 16; ++k) {
            const float* Tprev = (k == 2) ? src : slot(k - 2);
            k_prop<false><<<GRID_P, 256, 0, stream>>>(slot(k - 1), Tprev, slot(k),
                                                      off, degi, csrp);
            if ((k % CAD) == 0) {
                CombCfg cfg;
                for (int t = 0; t < nt; ++t) {
                    int si = scl[t];
                    cfg.c0[t] = 0.5f * C[0][si];
                    cfg.plane[t] = pln[t];
                    for (int m = 0; m < CAD; ++m) cfg.ck[t][m] = C[k - CAD + 1 + m][si];
                }
                launch_combine(nt, src, accb, cfg, (k == CAD) ? 1 : 0,
                               (k == 16) ? 1 : 0);
            }
        }
    };

    // ---- phase 1: xq -> hacc planes 0..3 (|h| per scale) ----
    {
        const int scl[4] = {0, 1, 2, 3};
        const int pln[4] = {0, 1, 2, 3};
        run_chain(xq, hacc, scl, pln, 4);
    }

    // ---- phase 2: 3 chains on hacc planes 0..2 ----
    {
        const int scl0[3] = {1, 2, 3}; const int pln0[3] = {0, 1, 3};
        run_chain(hacc + 0 * CHAIN_ELEMS, acc2, scl0, pln0, 3);
        const int scl1[2] = {2, 3};    const int pln1[2] = {2, 4};
        run_chain(hacc + 1 * CHAIN_ELEMS, acc2, scl1, pln1, 2);
        const int scl2[1] = {3};       const int pln2[1] = {5};
        run_chain(hacc + 2 * CHAIN_ELEMS, acc2, scl2, pln2, 1);
    }

    // ---- moments ----
    dim3 mg(3, NGRAPH);
    k_moments<<<mg, 256, 0, stream>>>(xq, hacc, acc2, out);
}

// Round 3
// 2451.971 us; speedup vs baseline: 2.2476x; 1.3519x over previous
//
#include <hip/hip_runtime.h>
#include <math.h>

#define NN 50000
#define NE 800000
#define NGRAPH 100
#define NPG 500
#define NB_SCAN 196
#define CHAIN_ELEMS ((size_t)NN * 64)
#define CH4 ((size_t)NN * 16)          // float4 elements per plane
#define GRID_PROP (NN / 4)             // 4 nodes (waves) per 256-thr block

typedef long long ll;

__device__ __forceinline__ void unpack(ll v, int& r, float& w) {
    r = (int)(v & 0xffffffffLL);
    w = __int_as_float((int)(v >> 32));
}

__device__ __forceinline__ float4 f4fma(float w, float4 v, float4 a) {
    a.x += w * v.x; a.y += w * v.y; a.z += w * v.z; a.w += w * v.w;
    return a;
}

// ---------------- setup kernels ----------------

__global__ void k_deg(const int* __restrict__ col, int* __restrict__ degi) {
    int e = blockIdx.x * blockDim.x + threadIdx.x;
    if (e < NE) atomicAdd(&degi[col[e]], 1);
}

__global__ void k_dh(const int* __restrict__ degi, float* __restrict__ dh) {
    int i = blockIdx.x * blockDim.x + threadIdx.x;
    if (i < NN) {
        int d = degi[i];
        dh[i] = d > 0 ? (float)(1.0 / sqrt((double)d)) : 0.0f;
    }
}

__global__ void k_bsum(const int* __restrict__ cnt, int* __restrict__ bsum) {
    __shared__ int sh[256];
    int i = blockIdx.x * 256 + threadIdx.x;
    sh[threadIdx.x] = (i < NN) ? cnt[i] : 0;
    __syncthreads();
    for (int s = 128; s > 0; s >>= 1) {
        if (threadIdx.x < s) sh[threadIdx.x] += sh[threadIdx.x + s];
        __syncthreads();
    }
    if (threadIdx.x == 0) bsum[blockIdx.x] = sh[0];
}

__global__ void k_bscan(const int* __restrict__ bsum, int* __restrict__ boff) {
    __shared__ int sh[2][256];
    int v = (threadIdx.x < NB_SCAN) ? bsum[threadIdx.x] : 0;
    int cur = 0;
    sh[0][threadIdx.x] = v;
    __syncthreads();
    for (int s = 1; s < 256; s <<= 1) {
        int val = sh[cur][threadIdx.x];
        if ((int)threadIdx.x >= s) val += sh[cur][threadIdx.x - s];
        sh[cur ^ 1][threadIdx.x] = val;
        cur ^= 1;
        __syncthreads();
    }
    if (threadIdx.x < NB_SCAN) boff[threadIdx.x] = sh[cur][threadIdx.x] - v;
}

__global__ void k_scan2(const int* __restrict__ cnt, const int* __restrict__ boff,
                        int* __restrict__ off) {
    __shared__ int sh[2][256];
    int i = blockIdx.x * 256 + threadIdx.x;
    int v = (i < NN) ? cnt[i] : 0;
    int cur = 0;
    sh[0][threadIdx.x] = v;
    __syncthreads();
    for (int s = 1; s < 256; s <<= 1) {
        int val = sh[cur][threadIdx.x];
        if ((int)threadIdx.x >= s) val += sh[cur][threadIdx.x - s];
        sh[cur ^ 1][threadIdx.x] = val;
        cur ^= 1;
        __syncthreads();
    }
    if (i < NN) off[i] = boff[blockIdx.x] + sh[cur][threadIdx.x] - v;
}

__global__ void k_fill(const int* __restrict__ row, const int* __restrict__ col,
                       const float* __restrict__ dh, const int* __restrict__ off,
                       int* __restrict__ cursor, ll* __restrict__ csrp) {
    int e = blockIdx.x * blockDim.x + threadIdx.x;
    if (e >= NE) return;
    int r = row[e], c = col[e];
    int pos = off[c] + atomicAdd(&cursor[c], 1);
    float w = dh[r] * dh[c];
    csrp[pos] = ((ll)__float_as_int(w) << 32) | (unsigned int)r;
}

// ---------------- recurrence kernel (R0-validated, fp32 [NN][64]) -----------
// wave = 1 node. lane = eg*16 + cq: eg = edge subgroup (0..3), cq = col quad.
// 256 B row gathers, 2 accumulators, plain (cached) loads.

template <bool INIT>
__global__ __launch_bounds__(256) void k_prop(
    const float* __restrict__ Tcur, const float* __restrict__ Tprev,
    float* __restrict__ Tnext, const int* __restrict__ off,
    const int* __restrict__ degi, const ll* __restrict__ csrp) {
    int node = blockIdx.x * 4 + (threadIdx.x >> 6);
    int lane = threadIdx.x & 63;
    int eg = lane >> 4;
    int cq = lane & 15;
    int s = off[node], e = s + degi[node];
    const float* tb = Tcur + (size_t)cq * 4;
    float4 a0 = make_float4(0.f, 0.f, 0.f, 0.f);
    float4 a1 = make_float4(0.f, 0.f, 0.f, 0.f);
    float4 pv = INIT ? make_float4(0.f, 0.f, 0.f, 0.f)
                     : *(const float4*)&Tprev[(size_t)node * 64 + cq * 4];
    int i = s;
    for (; i + 8 <= e; i += 8) {
        int r0, r1; float w0, w1;
        unpack(csrp[i + eg], r0, w0);
        unpack(csrp[i + 4 + eg], r1, w1);
        float4 v0 = *(const float4*)(tb + (size_t)r0 * 64);
        float4 v1 = *(const float4*)(tb + (size_t)r1 * 64);
        a0 = f4fma(w0, v0, a0);
        a1 = f4fma(w1, v1, a1);
    }
    for (; i < e; i += 4) {
        int idx = i + eg;
        bool act = idx < e;
        int r; float w;
        unpack(csrp[act ? idx : (e - 1)], r, w);
        if (!act) w = 0.f;
        float4 v = *(const float4*)(tb + (size_t)r * 64);
        a0 = f4fma(w, v, a0);
    }
    float4 g = make_float4(a0.x + a1.x, a0.y + a1.y, a0.z + a1.z, a0.w + a1.w);
    g.x += __shfl_xor(g.x, 16); g.y += __shfl_xor(g.y, 16);
    g.z += __shfl_xor(g.z, 16); g.w += __shfl_xor(g.w, 16);
    g.x += __shfl_xor(g.x, 32); g.y += __shfl_xor(g.y, 32);
    g.z += __shfl_xor(g.z, 32); g.w += __shfl_xor(g.w, 32);
    float4 t;
    if (INIT) {
        t = make_float4(-g.x, -g.y, -g.z, -g.w);
    } else {
        t = make_float4(-2.f * g.x - pv.x, -2.f * g.y - pv.y,
                        -2.f * g.z - pv.z, -2.f * g.w - pv.w);
    }
    if (eg == 0) *(float4*)&Tnext[(size_t)node * 64 + cq * 4] = t;
}

// ---------------- merged 3-source recurrence (phase 2) ----------------------
// One csrp load feeds gathers from 3 planes (plane stride CHAIN_ELEMS):
// 3x the MLP per index, 1/3 the index/loop/reduce overhead of 3 single props.
// csrp is software-pipelined one iteration ahead.

template <bool INIT>
__global__ __launch_bounds__(256, 6) void k_prop3(
    const float* __restrict__ Tcur, const float* __restrict__ Tprev,
    float* __restrict__ Tnext, const int* __restrict__ off,
    const int* __restrict__ degi, const ll* __restrict__ csrp) {
    int node = blockIdx.x * 4 + (threadIdx.x >> 6);
    int lane = threadIdx.x & 63;
    int eg = lane >> 4;
    int cq = lane & 15;
    int s = off[node], e = s + degi[node];
    const float* tb0 = Tcur + (size_t)cq * 4;
    const float* tb1 = tb0 + CHAIN_ELEMS;
    const float* tb2 = tb0 + 2 * CHAIN_ELEMS;
    float4 z = make_float4(0.f, 0.f, 0.f, 0.f);
    float4 a00 = z, a01 = z, a02 = z;
    float4 a10 = z, a11 = z, a12 = z;
    int i = s;
    ll pk0 = 0, pk1 = 0;
    if (i + 8 <= e) { pk0 = csrp[i + eg]; pk1 = csrp[i + 4 + eg]; }
    while (i + 8 <= e) {
        int inext = i + 8;
        ll nk0 = 0, nk1 = 0;
        if (inext + 8 <= e) { nk0 = csrp[inext + eg]; nk1 = csrp[inext + 4 + eg]; }
        int r0, r1; float w0, w1;
        unpack(pk0, r0, w0); unpack(pk1, r1, w1);
        size_t o0 = (size_t)r0 * 64, o1 = (size_t)r1 * 64;
        float4 v00 = *(const float4*)(tb0 + o0);
        float4 v01 = *(const float4*)(tb1 + o0);
        float4 v02 = *(const float4*)(tb2 + o0);
        float4 v10 = *(const float4*)(tb0 + o1);
        float4 v11 = *(const float4*)(tb1 + o1);
        float4 v12 = *(const float4*)(tb2 + o1);
        a00 = f4fma(w0, v00, a00);
        a01 = f4fma(w0, v01, a01);
        a02 = f4fma(w0, v02, a02);
        a10 = f4fma(w1, v10, a10);
        a11 = f4fma(w1, v11, a11);
        a12 = f4fma(w1, v12, a12);
        pk0 = nk0; pk1 = nk1; i = inext;
    }
    for (; i < e; i += 4) {
        int idx = i + eg;
        bool act = idx < e;
        int r; float w;
        unpack(csrp[act ? idx : (e - 1)], r, w);
        if (!act) w = 0.f;
        size_t o = (size_t)r * 64;
        a00 = f4fma(w, *(const float4*)(tb0 + o), a00);
        a01 = f4fma(w, *(const float4*)(tb1 + o), a01);
        a02 = f4fma(w, *(const float4*)(tb2 + o), a02);
    }
    float4 g0 = make_float4(a00.x + a10.x, a00.y + a10.y, a00.z + a10.z, a00.w + a10.w);
    float4 g1 = make_float4(a01.x + a11.x, a01.y + a11.y, a01.z + a11.z, a01.w + a11.w);
    float4 g2 = make_float4(a02.x + a12.x, a02.y + a12.y, a02.z + a12.z, a02.w + a12.w);
#define RED_EG(g) \
    g.x += __shfl_xor(g.x, 16); g.y += __shfl_xor(g.y, 16); \
    g.z += __shfl_xor(g.z, 16); g.w += __shfl_xor(g.w, 16); \
    g.x += __shfl_xor(g.x, 32); g.y += __shfl_xor(g.y, 32); \
    g.z += __shfl_xor(g.z, 32); g.w += __shfl_xor(g.w, 32);
    RED_EG(g0)
    RED_EG(g1)
    RED_EG(g2)
#undef RED_EG
    if (eg == 0) {
        size_t ob = (size_t)node * 64 + cq * 4;
        float4 t0, t1, t2;
        if (INIT) {
            t0 = make_float4(-g0.x, -g0.y, -g0.z, -g0.w);
            t1 = make_float4(-g1.x, -g1.y, -g1.z, -g1.w);
            t2 = make_float4(-g2.x, -g2.y, -g2.z, -g2.w);
        } else {
            float4 p0 = *(const float4*)&Tprev[ob];
            float4 p1 = *(const float4*)&Tprev[ob + CHAIN_ELEMS];
            float4 p2 = *(const float4*)&Tprev[ob + 2 * CHAIN_ELEMS];
            t0 = make_float4(-2.f * g0.x - p0.x, -2.f * g0.y - p0.y,
                             -2.f * g0.z - p0.z, -2.f * g0.w - p0.w);
            t1 = make_float4(-2.f * g1.x - p1.x, -2.f * g1.y - p1.y,
                             -2.f * g1.z - p1.z, -2.f * g1.w - p1.w);
            t2 = make_float4(-2.f * g2.x - p2.x, -2.f * g2.y - p2.y,
                             -2.f * g2.z - p2.z, -2.f * g2.w - p2.w);
        }
        *(float4*)&Tnext[ob] = t0;
        *(float4*)&Tnext[ob + CHAIN_ELEMS] = t1;
        *(float4*)&Tnext[ob + 2 * CHAIN_ELEMS] = t2;
    }
}

// ---------------- combine: acc planes from NS pool slots (float4) -----------

struct CombCfg {
    float c0[4];
    float ck[4][8];
    int   plane[4];
};

template <int NS, int NT>
__global__ __launch_bounds__(256) void k_combine(
    const float4* __restrict__ src0, const float4* __restrict__ pool,
    float4* __restrict__ accb, CombCfg cfg, int first, int doabs) {
    size_t v = (size_t)blockIdx.x * 256 + threadIdx.x;   // < NN*16
    float4 tv[NS];
#pragma unroll
    for (int m = 0; m < NS; ++m) tv[m] = pool[(size_t)m * CH4 + v];
    float4 s0 = first ? src0[v] : make_float4(0.f, 0.f, 0.f, 0.f);
#pragma unroll
    for (int t = 0; t < NT; ++t) {
        size_t o = (size_t)cfg.plane[t] * CH4 + v;
        float4 a;
        if (first) {
            float c = cfg.c0[t];
            a = make_float4(c * s0.x, c * s0.y, c * s0.z, c * s0.w);
        } else {
            a = accb[o];
        }
#pragma unroll
        for (int m = 0; m < NS; ++m) a = f4fma(cfg.ck[t][m], tv[m], a);
        if (doabs) a = make_float4(fabsf(a.x), fabsf(a.y), fabsf(a.z), fabsf(a.w));
        accb[o] = a;
    }
}

// ---------------- merged combine: 6 targets, 3 source planes per slot -------
// Target mapping (compile-time, rule-#20 safe):
//   t: (srcplane, scale, acc2 plane) =
//   (0,1,0) (0,2,1) (0,3,3) (1,2,2) (1,3,4) (2,3,5)

struct Comb3Cfg {
    float c0[6];
    float ck[6][4];
};

template <int NS>
__global__ __launch_bounds__(256) void k_comb3(
    const float4* __restrict__ src0, const float4* __restrict__ pool,
    float4* __restrict__ accb, Comb3Cfg cfg, int first, int doabs) {
    size_t v = (size_t)blockIdx.x * 256 + threadIdx.x;   // < NN*16
    float4 tv[NS][3];
#pragma unroll
    for (int m = 0; m < NS; ++m)
#pragma unroll
        for (int sp = 0; sp < 3; ++sp)
            tv[m][sp] = pool[((size_t)m * 3 + sp) * CH4 + v];
    float4 s0[3];
    if (first) {
#pragma unroll
        for (int sp = 0; sp < 3; ++sp) s0[sp] = src0[(size_t)sp * CH4 + v];
    }
    const int SP[6] = {0, 0, 0, 1, 1, 2};
    const int PL[6] = {0, 1, 3, 2, 4, 5};
#pragma unroll
    for (int t = 0; t < 6; ++t) {
        size_t o = (size_t)PL[t] * CH4 + v;
        float4 a;
        if (first) {
            float c = cfg.c0[t];
            float4 s = s0[SP[t]];
            a = make_float4(c * s.x, c * s.y, c * s.z, c * s.w);
        } else {
            a = accb[o];
        }
#pragma unroll
        for (int m = 0; m < NS; ++m) a = f4fma(cfg.ck[t][m], tv[m][SP[t]], a);
        if (doabs) a = make_float4(fabsf(a.x), fabsf(a.y), fabsf(a.z), fabsf(a.w));
        accb[o] = a;
    }
}

// ---------------- moments ----------------
__global__ void k_moments(const float* __restrict__ x, const float* __restrict__ hacc,
                          const float* __restrict__ acc2, float* __restrict__ out) {
    int g = blockIdx.y;
    int col = blockIdx.x * 256 + threadIdx.x;
    if (col >= 704) return;
    const float* src;
    int c0;
    if (col < 64)       { src = x;    c0 = col; }
    else if (col < 320) { int p = (col - 64) >> 6;  src = hacc + (size_t)p * CHAIN_ELEMS; c0 = (col - 64) & 63; }
    else                { int p = (col - 320) >> 6; src = acc2 + (size_t)p * CHAIN_ELEMS; c0 = (col - 320) & 63; }
    double s1 = 0, s2 = 0, s3 = 0, s4 = 0;
    int base = g * NPG;
    for (int i = 0; i < NPG; ++i) {
        double v = (double)src[(size_t)(base + i) * 64 + c0];
        double v2 = v * v;
        s1 += v; s2 += v2; s3 += v2 * v; s4 += v2 * v2;
    }
    double n = (double)NPG;
    double mu = s1 / n;
    double E2 = s2 / n, E3 = s3 / n, E4 = s4 / n;
    double m2 = E2 - mu * mu;
    double m3 = E3 - 3.0 * mu * E2 + 2.0 * mu * mu * mu;
    double m4 = E4 - 4.0 * mu * E3 + 6.0 * mu * mu * E2 - 3.0 * mu * mu * mu * mu;
    float m2f = (float)m2;
    float skew = 0.f, kurt = -3.f;
    if (m2f > 0.f) {
        skew = (float)(m3 / (m2 * sqrt(m2)));
        if (skew > 1e15f) skew = 0.f;
        kurt = (float)(m4 / (m2 * m2) - 3.0);
        if (kurt > 1e15f) kurt = -3.f;
    }
    size_t ob = (size_t)g * 2816 + col;
    out[ob]        = (float)mu;
    out[ob + 704]  = m2f;
    out[ob + 1408] = skew;
    out[ob + 2112] = kurt;
}

// ---------------- host ----------------

extern "C" void kernel_launch(void* const* d_in, const int* in_sizes, int n_in,
                              void* d_out, int out_size, void* d_ws, size_t ws_size,
                              hipStream_t stream) {
    const float* x = (const float*)d_in[0];
    const int* ei  = (const int*)d_in[1];
    const int* row = ei;
    const int* col = ei + NE;
    float* out = (float*)d_out;

    // Chebyshev coefficients [17][4], double precision (matches numpy)
    float C[17][4];
    {
        const int Nc = 17;
        const int scales[4] = {2, 4, 8, 16};
        for (int si = 0; si < 4; ++si) {
            double ker[17];
            for (int j = 0; j < Nc; ++j) {
                double num = cos(M_PI * (j + 0.5) / Nc);
                double b = -num;
                double v = pow(b, (double)(scales[si] / 2)) - pow(b, (double)scales[si]);
                if (v < 0) v = 0;
                ker[j] = sqrt(v);
            }
            for (int o = 0; o < Nc; ++o) {
                double acc = 0;
                for (int j = 0; j < Nc; ++j) acc += ker[j] * cos(M_PI * o * (j + 0.5) / Nc);
                C[o][si] = (float)(2.0 / Nc * acc);
            }
        }
    }

    // workspace carve. Plans:
    //   A: merged phase-2, CAD1=8, CAD2=4, pool 12 planes (~289 MB)
    //   B: merged phase-2, CAD1=4, CAD2=2, pool 6 planes  (~212 MB)
    //   C: unmerged (R0),  CAD1=4, CAD2=4, pool 4 planes  (~186 MB)
    int*   degi; float* dh; int* off; int* cursor; int* bsum; int* boff;
    ll*    csrp; float* pool; float* hacc; float* acc2;
    const int plans[3][4] = {{8, 4, 12, 1}, {4, 2, 6, 1}, {4, 4, 4, 0}};
    int CAD1 = 8, CAD2 = 4, MERGED = 1;
    for (int attempt = 0; attempt < 3; ++attempt) {
        CAD1 = plans[attempt][0];
        CAD2 = plans[attempt][1];
        int poolpl = plans[attempt][2];
        MERGED = plans[attempt][3];
        char* p = (char*)d_ws;
        auto alloc = [&](size_t bytes) -> void* {
            void* r = (void*)p;
            p += (bytes + 255) & ~(size_t)255;
            return r;
        };
        degi   = (int*)alloc((size_t)NN * 4);
        dh     = (float*)alloc((size_t)NN * 4);
        off    = (int*)alloc((size_t)NN * 4);
        cursor = (int*)alloc((size_t)NN * 4);
        bsum   = (int*)alloc((size_t)NB_SCAN * 4);
        boff   = (int*)alloc((size_t)NB_SCAN * 4);
        csrp   = (ll*)alloc((size_t)NE * 8);
        pool   = (float*)alloc((size_t)poolpl * CHAIN_ELEMS * 4);
        hacc   = (float*)alloc((size_t)4 * CHAIN_ELEMS * 4);
        acc2   = (float*)alloc((size_t)6 * CHAIN_ELEMS * 4);
        if ((size_t)(p - (char*)d_ws) <= ws_size) break;
    }

    hipMemsetAsync(degi, 0, (size_t)NN * 4, stream);
    hipMemsetAsync(cursor, 0, (size_t)NN * 4, stream);

    k_deg  <<<(NE + 255) / 256, 256, 0, stream>>>(col, degi);
    k_dh   <<<(NN + 255) / 256, 256, 0, stream>>>(degi, dh);
    k_bsum <<<NB_SCAN, 256, 0, stream>>>(degi, bsum);
    k_bscan<<<1, 256, 0, stream>>>(bsum, boff);
    k_scan2<<<NB_SCAN, 256, 0, stream>>>(degi, boff, off);
    k_fill <<<(NE + 255) / 256, 256, 0, stream>>>(row, col, dh, off, cursor, csrp);

    const int GRID_C = (int)(CH4 / 256);   // 3125

    auto slot = [&](int k, int cad) {
        return pool + (size_t)((k - 1) & (cad - 1)) * CHAIN_ELEMS;
    };

    auto launch_combine = [&](int nt, int cad, const float* src, float* accb,
                              CombCfg& cfg, int first, int doabs) {
        const float4* s4 = (const float4*)src;
        const float4* p4 = (const float4*)pool;
        float4* a4 = (float4*)accb;
        if (cad == 8) {
            if (nt == 4) k_combine<8, 4><<<GRID_C, 256, 0, stream>>>(s4, p4, a4, cfg, first, doabs);
            if (nt == 3) k_combine<8, 3><<<GRID_C, 256, 0, stream>>>(s4, p4, a4, cfg, first, doabs);
            if (nt == 2) k_combine<8, 2><<<GRID_C, 256, 0, stream>>>(s4, p4, a4, cfg, first, doabs);
            if (nt == 1) k_combine<8, 1><<<GRID_C, 256, 0, stream>>>(s4, p4, a4, cfg, first, doabs);
        } else {
            if (nt == 4) k_combine<4, 4><<<GRID_C, 256, 0, stream>>>(s4, p4, a4, cfg, first, doabs);
            if (nt == 3) k_combine<4, 3><<<GRID_C, 256, 0, stream>>>(s4, p4, a4, cfg, first, doabs);
            if (nt == 2) k_combine<4, 2><<<GRID_C, 256, 0, stream>>>(s4, p4, a4, cfg, first, doabs);
            if (nt == 1) k_combine<4, 1><<<GRID_C, 256, 0, stream>>>(s4, p4, a4, cfg, first, doabs);
        }
    };

    // single-source chain: src [NN,64] -> acc planes of accb
    auto run_chain = [&](const float* src, float* accb,
                         const int* scl, const int* pln, int nt, int cad) {
        k_prop<true><<<GRID_PROP, 256, 0, stream>>>(src, nullptr, slot(1, cad),
                                                    off, degi, csrp);
        for (int k = 2; k <= 16; ++k) {
            const float* Tprev = (k == 2) ? src : slot(k - 2, cad);
            k_prop<false><<<GRID_PROP, 256, 0, stream>>>(slot(k - 1, cad), Tprev,
                                                         slot(k, cad), off, degi, csrp);
            if ((k % cad) == 0) {
                CombCfg cfg;
                for (int t = 0; t < nt; ++t) {
                    int si = scl[t];
                    cfg.c0[t] = 0.5f * C[0][si];
                    cfg.plane[t] = pln[t];
                    for (int m = 0; m < cad; ++m) cfg.ck[t][m] = C[k - cad + 1 + m][si];
                }
                launch_combine(nt, cad, src, accb, cfg, (k == cad) ? 1 : 0,
                               (k == 16) ? 1 : 0);
            }
        }
    };

    // ---- phase 1: x -> hacc planes 0..3 (|h| per scale) ----
    {
        const int scl[4] = {0, 1, 2, 3};
        const int pln[4] = {0, 1, 2, 3};
        run_chain(x, hacc, scl, pln, 4, CAD1);
    }

    // ---- phase 2 ----
    if (MERGED) {
        // merged 3-source chain on hacc planes 0..2 -> acc2 planes 0..5
        auto slot3 = [&](int k) {
            return pool + (size_t)((k - 1) & (CAD2 - 1)) * 3 * CHAIN_ELEMS;
        };
        k_prop3<true><<<GRID_PROP, 256, 0, stream>>>(hacc, nullptr, slot3(1),
                                                     off, degi, csrp);
        for (int k = 2; k <= 16; ++k) {
            const float* Tprev = (k == 2) ? hacc : slot3(k - 2);
            k_prop3<false><<<GRID_PROP, 256, 0, stream>>>(slot3(k - 1), Tprev,
                                                          slot3(k), off, degi, csrp);
            if ((k % CAD2) == 0) {
                Comb3Cfg cfg;
                const int SI[6] = {1, 2, 3, 2, 3, 3};
                for (int t = 0; t < 6; ++t) {
                    cfg.c0[t] = 0.5f * C[0][SI[t]];
                    for (int m = 0; m < CAD2; ++m)
                        cfg.ck[t][m] = C[k - CAD2 + 1 + m][SI[t]];
                }
                if (CAD2 == 4)
                    k_comb3<4><<<GRID_C, 256, 0, stream>>>(
                        (const float4*)hacc, (const float4*)pool, (float4*)acc2,
                        cfg, (k == CAD2) ? 1 : 0, (k == 16) ? 1 : 0);
                else
                    k_comb3<2><<<GRID_C, 256, 0, stream>>>(
                        (const float4*)hacc, (const float4*)pool, (float4*)acc2,
                        cfg, (k == CAD2) ? 1 : 0, (k == 16) ? 1 : 0);
            }
        }
    } else {
        const int scl0[3] = {1, 2, 3}; const int pln0[3] = {0, 1, 3};
        run_chain(hacc + 0 * CHAIN_ELEMS, acc2, scl0, pln0, 3, CAD2);
        const int scl1[2] = {2, 3};    const int pln1[2] = {2, 4};
        run_chain(hacc + 1 * CHAIN_ELEMS, acc2, scl1, pln1, 2, CAD2);
        const int scl2[1] = {3};       const int pln2[1] = {5};
        run_chain(hacc + 2 * CHAIN_ELEMS, acc2, scl2, pln2, 1, CAD2);
    }

    // ---- moments ----
    dim3 mg(3, NGRAPH);
    k_moments<<<mg, 256, 0, stream>>>(x, hacc, acc2, out);
}